// Round 6
// baseline (82.882 us; speedup 1.0000x reference)
//
#include <hip/hip_runtime.h>

#define OUTN 512
#define NCTL 64
#define BATCH 16

// clang-native 16B vector type (HIP's float4 is a class type that
// __builtin_nontemporal_store rejects)
typedef float fx4 __attribute__((ext_vector_type(4)));

// One block per (b,u) output row, 256 threads, 2 v-points per thread
// (v = t and t+256: 8 adjacent lanes share a vspan -> A-reads broadcast,
//  conflict-free).
// Phase 1: A[n][c] = sum_r Nu[u][r] * ctrl[b][su-3+r][n][c]   (LDS, 1 KB)
// Phase 2: per v: Sw[c] = sum_s Nv[v][s]*A[vspan[v]-3+s][c]; xyz*rcp(w)
//          -> staged into S[512*3] (dword-stride-3 writes: 2-way alias, free)
// Phase 3: dense NON-TEMPORAL float4 writeback (streams past L2; avoids
//          contention with the harness's 256MiB poison-fill dirty lines).
__global__ __launch_bounds__(256) void surfeval_kernel(
    const float* __restrict__ ctrl,   // (B,64,64,4)
    const int*   __restrict__ uspan,  // (512)
    const int*   __restrict__ vspan,  // (512)
    const float* __restrict__ Nu,     // (512,4)
    const float* __restrict__ Nv,     // (512,4)
    float*       __restrict__ out)    // (B,512,512,3)
{
    __shared__ float A[NCTL][4];    // 1 KB
    __shared__ float S[OUTN * 3];   // 6 KB staged output row

    const int t = threadIdx.x;
    const int u = blockIdx.x;
    const int b = blockIdx.y;

    // ---- Prefetch phase-2 inputs early (independent of phase 1) ----
    const int v0 = t;
    const int v1 = t + 256;
    const int sv0 = vspan[v0];
    const int sv1 = vspan[v1];
    const float4 nv0 = ((const float4*)Nv)[v0];
    const float4 nv1 = ((const float4*)Nv)[v1];

    // ---- Phase 1: contract over u-direction into A ----
    const int su = uspan[u];
    const float4 nu = ((const float4*)Nu)[u];
    {
        // thread t -> element t of each of 4 contiguous ctrl rows (1 KB
        // coalesced per row-load)
        const float* p = ctrl + ((size_t)b * NCTL + (size_t)(su - 3)) * (NCTL * 4) + t;
        A[t >> 2][t & 3] = nu.x * p[0]
                         + nu.y * p[NCTL * 4]
                         + nu.z * p[2 * NCTL * 4]
                         + nu.w * p[3 * NCTL * 4];
    }
    __syncthreads();

    // ---- Phase 2: compute 2 points, stage into S ----
    {
        const float4* Af = (const float4*)(&A[sv0 - 3][0]);
        const float4 s0 = Af[0], s1 = Af[1], s2 = Af[2], s3 = Af[3];
        const float sx = nv0.x * s0.x + nv0.y * s1.x + nv0.z * s2.x + nv0.w * s3.x;
        const float sy = nv0.x * s0.y + nv0.y * s1.y + nv0.z * s2.y + nv0.w * s3.y;
        const float sz = nv0.x * s0.z + nv0.y * s1.z + nv0.z * s2.z + nv0.w * s3.z;
        const float sw = nv0.x * s0.w + nv0.y * s1.w + nv0.z * s2.w + nv0.w * s3.w;
        const float inv = __builtin_amdgcn_rcpf(sw);   // rel err ~1e-6 << 7.8e-3 tol
        S[3 * v0 + 0] = sx * inv;
        S[3 * v0 + 1] = sy * inv;
        S[3 * v0 + 2] = sz * inv;
    }
    {
        const float4* Af = (const float4*)(&A[sv1 - 3][0]);
        const float4 s0 = Af[0], s1 = Af[1], s2 = Af[2], s3 = Af[3];
        const float sx = nv1.x * s0.x + nv1.y * s1.x + nv1.z * s2.x + nv1.w * s3.x;
        const float sy = nv1.x * s0.y + nv1.y * s1.y + nv1.z * s2.y + nv1.w * s3.y;
        const float sz = nv1.x * s0.z + nv1.y * s1.z + nv1.z * s2.z + nv1.w * s3.z;
        const float sw = nv1.x * s0.w + nv1.y * s1.w + nv1.z * s2.w + nv1.w * s3.w;
        const float inv = __builtin_amdgcn_rcpf(sw);
        S[3 * v1 + 0] = sx * inv;
        S[3 * v1 + 1] = sy * inv;
        S[3 * v1 + 2] = sz * inv;
    }
    __syncthreads();

    // ---- Phase 3: dense coalesced non-temporal writeback (384 fx4s) ----
    fx4* og = (fx4*)(out + ((size_t)b * OUTN + (size_t)u) * (OUTN * 3));
    const fx4* Sf = (const fx4*)S;
    __builtin_nontemporal_store(Sf[t], og + t);
    if (t < (OUTN * 3 / 4) - 256) {          // 128 remaining; waves 0-1, uniform
        __builtin_nontemporal_store(Sf[256 + t], og + 256 + t);
    }
}

extern "C" void kernel_launch(void* const* d_in, const int* in_sizes, int n_in,
                              void* d_out, int out_size, void* d_ws, size_t ws_size,
                              hipStream_t stream) {
    const float* ctrl  = (const float*)d_in[0];
    const int*   uspan = (const int*)d_in[1];
    const int*   vspan = (const int*)d_in[2];
    const float* Nu    = (const float*)d_in[3];
    const float* Nv    = (const float*)d_in[4];
    float* out = (float*)d_out;

    dim3 grid(OUTN, BATCH);   // 8192 blocks
    surfeval_kernel<<<grid, 256, 0, stream>>>(ctrl, uspan, vspan, Nu, Nv, out);
}

// Round 7
// 80.653 us; speedup vs baseline: 1.0276x; 1.0276x over previous
//
#include <hip/hip_runtime.h>

#define OUTN 512
#define NCTL 64
#define BATCH 16
#define ROWS 4   // u-rows per block

// Grid (OUTN/ROWS, BATCH) = (128,16) = 2048 blocks, 256 threads.
// Each block computes ROWS consecutive u-rows for one batch b.
// v-side operands (vspan, Nv) are loaded ONCE per thread and reused for all
// ROWS rows; one barrier total; 16 independent phase-1 loads issue together.
// Lane=v mapping keeps phase-2 LDS reads broadcast/conflict-free (8 adjacent
// lanes share a vspan; distinct addresses cover banks 0..31 exactly once).
//
// Session summary (rounds 0-6): store pattern (scalar stride-12 vs LDS-staged
// dense float4 vs non-temporal), grid shape (8192 vs 2048 blocks), barrier
// count, and rcp-vs-div are ALL neutral within +/-1.5us; measured dur_us is
// dominated by the harness's ~46us 256MiB poison fill + smaller poisons. This
// variant was the best measured (79.79us).
__global__ __launch_bounds__(256) void surfeval_kernel(
    const float* __restrict__ ctrl,   // (B,64,64,4)
    const int*   __restrict__ uspan,  // (512)
    const int*   __restrict__ vspan,  // (512)
    const float* __restrict__ Nu,     // (512,4)
    const float* __restrict__ Nv,     // (512,4)
    float*       __restrict__ out)    // (B,512,512,3)
{
    __shared__ float A[ROWS][NCTL][4];   // 4 KB

    const int t  = threadIdx.x;
    const int u0 = blockIdx.x * ROWS;
    const int b  = blockIdx.y;

    // ---- v-side operands: load once, reuse for all ROWS rows ----
    const int v0 = t;
    const int v1 = t + 256;
    const int sv0 = vspan[v0];
    const int sv1 = vspan[v1];
    const float4 nv0 = ((const float4*)Nv)[v0];
    const float4 nv1 = ((const float4*)Nv)[v1];

    // ---- Phase 1: A[j][n][c] = sum_r Nu[u0+j][r]*ctrl[b][su_j-3+r][n][c] ----
    // 16 independent coalesced loads (4 rows x 4 taps) -> deep MLP.
    const float* cbase = ctrl + (size_t)b * (NCTL * NCTL * 4) + t;
    #pragma unroll
    for (int j = 0; j < ROWS; ++j) {
        const int    su = uspan[u0 + j];             // uniform -> s_load
        const float4 nu = ((const float4*)Nu)[u0 + j];
        const float* p  = cbase + (size_t)(su - 3) * (NCTL * 4);
        A[j][t >> 2][t & 3] = nu.x * p[0]
                            + nu.y * p[NCTL * 4]
                            + nu.z * p[2 * NCTL * 4]
                            + nu.w * p[3 * NCTL * 4];
    }
    __syncthreads();

    // ---- Phase 2: 2 v-points x ROWS rows per thread ----
    float* __restrict__ obase = out + ((size_t)(b * OUTN + u0)) * (OUTN * 3);
    #pragma unroll
    for (int j = 0; j < ROWS; ++j) {
        const float* Aj = &A[j][0][0];
        float* __restrict__ orow = obase + (size_t)j * (OUTN * 3);
        {
            const float4* Af = (const float4*)(Aj + ((sv0 - 3) << 2));
            const float4 s0 = Af[0], s1 = Af[1], s2 = Af[2], s3 = Af[3];
            const float sx = nv0.x * s0.x + nv0.y * s1.x + nv0.z * s2.x + nv0.w * s3.x;
            const float sy = nv0.x * s0.y + nv0.y * s1.y + nv0.z * s2.y + nv0.w * s3.y;
            const float sz = nv0.x * s0.z + nv0.y * s1.z + nv0.z * s2.z + nv0.w * s3.z;
            const float sw = nv0.x * s0.w + nv0.y * s1.w + nv0.z * s2.w + nv0.w * s3.w;
            const float inv = __builtin_amdgcn_rcpf(sw);  // rel err ~1e-6 << tol
            orow[v0 * 3 + 0] = sx * inv;
            orow[v0 * 3 + 1] = sy * inv;
            orow[v0 * 3 + 2] = sz * inv;
        }
        {
            const float4* Af = (const float4*)(Aj + ((sv1 - 3) << 2));
            const float4 s0 = Af[0], s1 = Af[1], s2 = Af[2], s3 = Af[3];
            const float sx = nv1.x * s0.x + nv1.y * s1.x + nv1.z * s2.x + nv1.w * s3.x;
            const float sy = nv1.x * s0.y + nv1.y * s1.y + nv1.z * s2.y + nv1.w * s3.y;
            const float sz = nv1.x * s0.z + nv1.y * s1.z + nv1.z * s2.z + nv1.w * s3.z;
            const float sw = nv1.x * s0.w + nv1.y * s1.w + nv1.z * s2.w + nv1.w * s3.w;
            const float inv = __builtin_amdgcn_rcpf(sw);
            orow[v1 * 3 + 0] = sx * inv;
            orow[v1 * 3 + 1] = sy * inv;
            orow[v1 * 3 + 2] = sz * inv;
        }
    }
}

extern "C" void kernel_launch(void* const* d_in, const int* in_sizes, int n_in,
                              void* d_out, int out_size, void* d_ws, size_t ws_size,
                              hipStream_t stream) {
    const float* ctrl  = (const float*)d_in[0];
    const int*   uspan = (const int*)d_in[1];
    const int*   vspan = (const int*)d_in[2];
    const float* Nu    = (const float*)d_in[3];
    const float* Nv    = (const float*)d_in[4];
    float* out = (float*)d_out;

    dim3 grid(OUTN / ROWS, BATCH);   // 2048 blocks -> 8/CU, one generation
    surfeval_kernel<<<grid, 256, 0, stream>>>(ctrl, uspan, vspan, Nu, Nv, out);
}